// Round 6
// baseline (241.625 us; speedup 1.0000x reference)
//
#include <hip/hip_runtime.h>

#define C_ 512
#define L_ 784
#define K_ 64
#define EPS_ 1e-12f

typedef _Float16 half_t;
typedef _Float16 half4 __attribute__((ext_vector_type(4)));
typedef float float4v __attribute__((ext_vector_type(4)));

// ---------------------------------------------------------------------------
// kF v5b: zero-staging fused logits -> softmax -> LAGGED partial agg with ONE
// barrier per subtile (r4 had two; barrier drains at 1 block/CU were the
// dominant stall).  grid (4, 64), block 1024 (16 waves = 4 kt x 4 cs).
// v5b == v5 minus the amdgpu_waves_per_eu(4,4) attribute (suspected cause of
// the r5 container failure: it stacks a hard waves/EU constraint on top of
// __launch_bounds__' own occupancy lowering).
//
// Per 16-l subtile s (single barrier):
//   0. bn[i] = cvt(pf[i])                  // x frags prefetched last subtile
//   1. issue pf[i] loads for s+1; sched_barrier(0) pins placement
//   2. logits: T = mfma(bn[i], I) transpose; lc[i&3] += mfma(T_h, wf[i])
//      (4 independent accumulators -- no dependent MFMA chain)
//   3. sl[s&1][l][k][cs] partials; __syncthreads()  (the ONLY barrier)
//   4. softmax: wave=l-row, lane=k, shfl_xor trees; ah[s&1][k][l]; asum
//   5. agg(s-1): agc[i] += mfma(A=ah[(s-1)&1], B=bhp[i])
//      SAFE: softmax(s-1) precedes barrier(s) in every wave's program order.
//   6. bhp = bn
// Tail: barrier; agg(NT-1) from bhp.
// MFMA maps verified end-to-end in r3/r4 (passed, absmax 1.2e-4):
//   A: m=lane&15, kk=q*4+j; B: n=lane&15, kk=q*4+j; D: row=q*4+r, col=lane&15.
// ---------------------------------------------------------------------------
__global__ __launch_bounds__(1024) void kF(const float* __restrict__ x,
                                           const float* __restrict__ w,
                                           float* __restrict__ aggP,
                                           float* __restrict__ asumP) {
    __shared__ float  sl[2][16 * 64 * 4];  // [buf][l][k][cs] logits partials (32 KB)
    __shared__ half_t ah[2][64 * 20];      // [buf][k][16 l + pad4] (5 KB)

    const int t    = threadIdx.x;
    const int n    = blockIdx.y;
    const int bx   = blockIdx.x;
    const int l0   = bx * 192;
    const int NT   = (bx == 3) ? 13 : 12;
    const int wv   = t >> 6;
    const int lane = t & 63;
    const int m16  = lane & 15;
    const int q    = lane >> 4;
    const int kt   = wv & 3;   // k-tile (16 k)
    const int cs   = wv >> 2;  // c-segment (128 c = 8 tiles of 16)

    const float* xn = x + (size_t)n * (C_ * L_);
    // lane's x row base: row (cs*8+i)*16+m16, col l0+4q; tile i at +i*16*L_
    const float* xr = xn + (size_t)(cs * 128 + m16) * L_ + l0 + 4 * q;

    // prefetch subtile 0 first: maximum latency cover
    float4v pf[8];
#pragma unroll
    for (int i = 0; i < 8; ++i)
        pf[i] = *(const float4v*)(xr + (size_t)i * 16 * L_);

    // w fragments (B-style): lane m16 -> k row, elems j -> c = cs*128+i*16+4q+j
    half4 wf[8];
#pragma unroll
    for (int i = 0; i < 8; ++i) {
        float4v f = *(const float4v*)(w + (size_t)(kt * 16 + m16) * C_ +
                                      cs * 128 + i * 16 + 4 * q);
        wf[i] = half4{(half_t)f[0], (half_t)f[1], (half_t)f[2], (half_t)f[3]};
    }
    // identity B-fragment: I[kk=4q+j][n=m16]
    half4 ifr;
#pragma unroll
    for (int j = 0; j < 4; ++j) ifr[j] = (half_t)((4 * q + j == m16) ? 1.0f : 0.0f);

    const float4v z4 = {0.f, 0.f, 0.f, 0.f};
    float4v agc[8];
#pragma unroll
    for (int i = 0; i < 8; ++i) agc[i] = z4;
    half4 bhp[8];              // previous subtile's x frags (agg B-operands)
    float asum_reg = 0.f;

    for (int s = 0; s < NT; ++s) {
        // 0. convert staged fragments for THIS subtile
        half4 bn[8];
#pragma unroll
        for (int i = 0; i < 8; ++i)
            bn[i] = half4{(half_t)pf[i][0], (half_t)pf[i][1],
                          (half_t)pf[i][2], (half_t)pf[i][3]};
        // 1. issue next-subtile loads; consumed at next iteration's cvt
        if (s + 1 < NT) {
            const float* p = xr + (s + 1) * 16;
#pragma unroll
            for (int i = 0; i < 8; ++i)
                pf[i] = *(const float4v*)(p + (size_t)i * 16 * L_);
        }
        __builtin_amdgcn_sched_barrier(0);   // pin prefetch issue point
        // 2. logits: transpose via identity-MFMA; 4 independent accumulators
        float4v lc[4] = {z4, z4, z4, z4};
#pragma unroll
        for (int i = 0; i < 8; ++i) {
            float4v xt = __builtin_amdgcn_mfma_f32_16x16x16f16(bn[i], ifr, z4, 0, 0, 0);
            half4 a4 = {(half_t)xt[0], (half_t)xt[1], (half_t)xt[2], (half_t)xt[3]};
            lc[i & 3] = __builtin_amdgcn_mfma_f32_16x16x16f16(a4, wf[i], lc[i & 3], 0, 0, 0);
        }
        float4v lac = (lc[0] + lc[1]) + (lc[2] + lc[3]);
        // 3. D[l][k]: row 4q+r = l_local, col m16 = k_local
        float* slb = sl[s & 1];
#pragma unroll
        for (int r = 0; r < 4; ++r)
            slb[((4 * q + r) * 64 + kt * 16 + m16) * 4 + cs] = lac[r];
        __syncthreads();   // the ONLY barrier per subtile
        // 4. softmax: wave wv = l-row, lane = k
        {
            float4v p4 = *(const float4v*)&slb[(wv * 64 + lane) * 4];
            float lg = p4[0] + p4[1] + p4[2] + p4[3];
            float mx = lg;
#pragma unroll
            for (int off = 32; off; off >>= 1) mx = fmaxf(mx, __shfl_xor(mx, off, 64));
            float e = __expf(lg - mx);
            float sm = e;
#pragma unroll
            for (int off = 32; off; off >>= 1) sm += __shfl_xor(sm, off, 64);
            float a = e / sm;
            asum_reg += a;
            ah[s & 1][lane * 20 + wv] = (half_t)a;
        }
        // 5. lagged agg(s-1): ah[(s-1)&1] complete (softmax(s-1) preceded
        //    barrier(s) in all waves); bhp holds x frags of subtile s-1.
        if (s > 0) {
            half4 aA = *(const half4*)&ah[(s - 1) & 1][(kt * 16 + m16) * 20 + 4 * q];
#pragma unroll
            for (int i = 0; i < 8; ++i)
                agc[i] = __builtin_amdgcn_mfma_f32_16x16x16f16(aA, bhp[i], agc[i], 0, 0, 0);
        }
        // 6. roll fragments
#pragma unroll
        for (int i = 0; i < 8; ++i) bhp[i] = bn[i];
    }

    // tail: final subtile's agg (ah[(NT-1)&1] needs a barrier to be visible)
    __syncthreads();
    {
        half4 aA = *(const half4*)&ah[(NT - 1) & 1][(kt * 16 + m16) * 20 + 4 * q];
#pragma unroll
        for (int i = 0; i < 8; ++i)
            agc[i] = __builtin_amdgcn_mfma_f32_16x16x16f16(aA, bhp[i], agc[i], 0, 0, 0);
    }

    // ---- epilogue: asum reduce (sl[0] reused) + direct coalesced agg stores ----
    float* red = sl[0];
    red[wv * 64 + lane] = asum_reg;
    __syncthreads();
    if (t < 64) {
        float s_ = 0.f;
#pragma unroll
        for (int j = 0; j < 16; ++j) s_ += red[j * 64 + t];
        asumP[((size_t)n * 4 + bx) * 64 + t] = s_;
    }
    float* ap = aggP + (((size_t)n * 4 + bx) * 64) * (size_t)C_;
#pragma unroll
    for (int i = 0; i < 8; ++i)
#pragma unroll
        for (int r = 0; r < 4; ++r)
            ap[(size_t)(kt * 16 + 4 * q + r) * C_ + (cs * 8 + i) * 16 + m16] = agc[i][r];
}

// ---------------------------------------------------------------------------
// kC: reduce 4 agg partials, vlad = agg - asum*cent, intra-normalize per
// (n,k) over C; global norm is exactly 8.  grid (16,64) = 1024 blocks,
// 256 thr, ONE k-row per wave.  float4 loads/stores.
// ---------------------------------------------------------------------------
__global__ __launch_bounds__(256) void kC(const float* __restrict__ aggP,
                                          const float* __restrict__ cent,
                                          const float* __restrict__ asumP,
                                          float* __restrict__ out) {
    __shared__ float asumS[4];
    const int t  = threadIdx.x;
    const int n  = blockIdx.y;
    const int k0 = blockIdx.x * 4;
    if (t < 4) {
        float s = 0.f;
        for (int j = 0; j < 4; ++j) s += asumP[((size_t)n * 4 + j) * 64 + k0 + t];
        asumS[t] = s;
    }
    __syncthreads();
    const int wv   = t >> 6;
    const int lane = t & 63;
    const int k    = k0 + wv;
    const float as = asumS[wv];
    const float* a0 = aggP + (((size_t)n * 4 + 0) * 64 + k) * C_;
    const float* a1 = aggP + (((size_t)n * 4 + 1) * 64 + k) * C_;
    const float* a2 = aggP + (((size_t)n * 4 + 2) * 64 + k) * C_;
    const float* a3 = aggP + (((size_t)n * 4 + 3) * 64 + k) * C_;
    const float* cp = cent + (size_t)k * C_;
    float4v v[2];
    float ss = 0.f;
#pragma unroll
    for (int j = 0; j < 2; ++j) {
        const int c = 4 * lane + 256 * j;
        float4v val = *(const float4v*)(a0 + c);
        val = val + *(const float4v*)(a1 + c);
        val = val + *(const float4v*)(a2 + c);
        val = val + *(const float4v*)(a3 + c);
        float4v c4 = *(const float4v*)(cp + c);
#pragma unroll
        for (int e = 0; e < 4; ++e) {
            val[e] -= as * c4[e];
            ss += val[e] * val[e];
        }
        v[j] = val;
    }
#pragma unroll
    for (int off = 32; off; off >>= 1) ss += __shfl_xor(ss, off, 64);
    const float scale = 1.f / (fmaxf(sqrtf(ss), EPS_) * 8.f);
    float* op = out + (size_t)n * (K_ * C_) + (size_t)k * C_;
#pragma unroll
    for (int j = 0; j < 2; ++j) {
        float4v o = v[j];
#pragma unroll
        for (int e = 0; e < 4; ++e) o[e] *= scale;
        *(float4v*)(op + 4 * lane + 256 * j) = o;
    }
}

extern "C" void kernel_launch(void* const* d_in, const int* in_sizes, int n_in,
                              void* d_out, int out_size, void* d_ws, size_t ws_size,
                              hipStream_t stream) {
    (void)in_sizes; (void)n_in; (void)out_size; (void)ws_size;
    const float* x    = (const float*)d_in[0];   // (64, 512, 28, 28) fp32
    const float* w    = (const float*)d_in[1];   // (64, 512) fp32
    const float* cent = (const float*)d_in[2];   // (64, 512) fp32
    float* out = (float*)d_out;                  // (64, 32768) fp32

    // ws: aggP f32 [64 n][4 bx][64 k][512 c] = 33.6 MB ; asumP f32 [64][4][64]
    // = 64 KB.  Total 33.7 MB (ws_size >= 46 MB known-good).
    char* base = (char*)d_ws;
    float* aggP  = (float*)base;
    float* asumP = aggP + (size_t)64 * 4 * 64 * 512;

    kF<<<dim3(4, 64), 1024, 0, stream>>>(x, w, aggP, asumP);
    kC<<<dim3(16, 64), 256, 0, stream>>>(aggP, cent, asumP, out);
}

// Round 7
// 172.463 us; speedup vs baseline: 1.4010x; 1.4010x over previous
//
#include <hip/hip_runtime.h>

#define C_ 512
#define L_ 784
#define K_ 64
#define EPS_ 1e-12f

typedef _Float16 half_t;
typedef _Float16 half4 __attribute__((ext_vector_type(4)));
typedef float float4v __attribute__((ext_vector_type(4)));

// ---------------------------------------------------------------------------
// kF v6: r4's proven 2-barrier skeleton + LDS-staged x (dedup across kt) and
// no register prefetch array -> no scratch spills (r6's regression: VGPR=64
// budget vs ~112 live => +28 MB spill WRITE, +85 MB FETCH).
// grid (4, 64), block 1024 (16 waves = 4 kt x 4 cs).
//
// x staging: 32 tiles (4 cs x 8 i) of 16c x 16l fp32, each tile 1 KB.
// Wave wv stages tiles 2wv, 2wv+1: one dwordx4 per lane per tile
//   (lane j -> c = base_c + (j&15), l = ls + 4*(j>>4)), stored at slot j
//   -> reader lane (m16,q) reads slot lane = its own fragment. 2-way banks.
// Per 16-l subtile s (two barriers, as r4):
//   0. g0,g1 = dwordx4 loads for subtile s+1 (transient; sched_barrier pin)
//   1. bn[i] = cvt(ds_read_b128 xs[s&1]); logits: T = mfma(bn,I) transpose,
//      lc[i&3] += mfma(T_h, wf[i])
//   2. sl[l][k][cs] partials; barrier A
//   3. softmax: wave=l-row, lane=k, shfl_xor trees; ah[k][l]; asum
//   4. ds_write g0,g1 -> xs[(s+1)&1]   (epoch A..B; readers after B)
//   5. barrier B; agg: agc[i] += mfma(A=ah, B=bn[i])  (bn still in regs)
// MFMA maps verified end-to-end r3/r4/r6 (passed, absmax 1.2e-4):
//   A: m=lane&15, kk=q*4+j; B: n=lane&15, kk=q*4+j; D: row=q*4+r, col=lane&15.
// ---------------------------------------------------------------------------
__global__ __launch_bounds__(1024) void kF(const float* __restrict__ x,
                                           const float* __restrict__ w,
                                           float* __restrict__ aggP,
                                           float* __restrict__ asumP) {
    __shared__ float  xs[2][32 * 256];   // 64 KB: [buf][tile = cs*8+i][slot*4]
    __shared__ float  sl[16 * 64 * 4];   // 16 KB: [l][k][cs] partials / asum buf
    __shared__ half_t ah[64 * 20];       // 2.5 KB: a fp16 [k][16 l + pad]

    const int t    = threadIdx.x;
    const int n    = blockIdx.y;
    const int bx   = blockIdx.x;
    const int l0   = bx * 192;
    const int NT   = (bx == 3) ? 13 : 12;
    const int wv   = t >> 6;
    const int lane = t & 63;
    const int m16  = lane & 15;
    const int q    = lane >> 4;
    const int kt   = wv & 3;   // k-tile (16 k)
    const int cs   = wv >> 2;  // c-segment (128 c = 8 tiles of 16)

    const float* xn = x + (size_t)n * (C_ * L_);

    // staging assignment: wave wv owns tiles T0 = 2wv, T0+1 (tile T: cs=T>>3, i=T&7)
    const int T0 = 2 * wv;
    const float* src0 = xn + (size_t)((T0 >> 3) * 128 + (T0 & 7) * 16 + m16) * L_ + l0 + 4 * q;
    const float* src1 = xn + (size_t)(((T0 + 1) >> 3) * 128 + ((T0 + 1) & 7) * 16 + m16) * L_ + l0 + 4 * q;

    // stage subtile 0
    {
        float4v g0 = *(const float4v*)src0;
        float4v g1 = *(const float4v*)src1;
        *(float4v*)&xs[0][T0 * 256 + lane * 4]       = g0;
        *(float4v*)&xs[0][(T0 + 1) * 256 + lane * 4] = g1;
    }

    // w fragments (B-style): lane m16 -> k row, elems j -> c = cs*128+i*16+4q+j
    half4 wf[8];
#pragma unroll
    for (int i = 0; i < 8; ++i) {
        float4v f = *(const float4v*)(w + (size_t)(kt * 16 + m16) * C_ +
                                      cs * 128 + i * 16 + 4 * q);
        wf[i] = half4{(half_t)f[0], (half_t)f[1], (half_t)f[2], (half_t)f[3]};
    }
    // identity B-fragment: I[kk=4q+j][n=m16]
    half4 ifr;
#pragma unroll
    for (int j = 0; j < 4; ++j) ifr[j] = (half_t)((4 * q + j == m16) ? 1.0f : 0.0f);

    const float4v z4 = {0.f, 0.f, 0.f, 0.f};
    float4v agc[8];
#pragma unroll
    for (int i = 0; i < 8; ++i) agc[i] = z4;
    float asum_reg = 0.f;

    __syncthreads();

    for (int s = 0; s < NT; ++s) {
        // 0. transient prefetch of subtile s+1 (2 dwordx4/wave; LDS-written at step 4)
        float4v g0, g1;
        const bool pf = (s + 1 < NT);
        if (pf) {
            g0 = *(const float4v*)(src0 + 16 * (s + 1));
            g1 = *(const float4v*)(src1 + 16 * (s + 1));
        }
        __builtin_amdgcn_sched_barrier(0);   // pin load issue at loop top
        // 1. fragments for subtile s from LDS + logits (transpose-MFMA trick)
        const float* xb = &xs[s & 1][(cs * 8) * 256];
        half4 bn[8];
        float4v lc[4] = {z4, z4, z4, z4};
#pragma unroll
        for (int i = 0; i < 8; ++i) {
            float4v f = *(const float4v*)&xb[i * 256 + lane * 4];
            bn[i] = half4{(half_t)f[0], (half_t)f[1], (half_t)f[2], (half_t)f[3]};
            float4v xt = __builtin_amdgcn_mfma_f32_16x16x16f16(bn[i], ifr, z4, 0, 0, 0);
            half4 a4 = {(half_t)xt[0], (half_t)xt[1], (half_t)xt[2], (half_t)xt[3]};
            lc[i & 3] = __builtin_amdgcn_mfma_f32_16x16x16f16(a4, wf[i], lc[i & 3], 0, 0, 0);
        }
        float4v lac = (lc[0] + lc[1]) + (lc[2] + lc[3]);
        // 2. D[l][k]: row 4q+r = l_local, col m16 = k_local
#pragma unroll
        for (int r = 0; r < 4; ++r)
            sl[((4 * q + r) * 64 + kt * 16 + m16) * 4 + cs] = lac[r];
        __syncthreads();   // barrier A
        // 3. softmax: wave wv = l-row, lane = k
        {
            float4v p4 = *(const float4v*)&sl[(wv * 64 + lane) * 4];
            float lg = p4[0] + p4[1] + p4[2] + p4[3];
            float mx = lg;
#pragma unroll
            for (int off = 32; off; off >>= 1) mx = fmaxf(mx, __shfl_xor(mx, off, 64));
            float e = __expf(lg - mx);
            float sm = e;
#pragma unroll
            for (int off = 32; off; off >>= 1) sm += __shfl_xor(sm, off, 64);
            float a = e / sm;
            asum_reg += a;
            ah[lane * 20 + wv] = (half_t)a;
        }
        // 4. write staged subtile s+1 into the other xs buffer (read after B)
        if (pf) {
            *(float4v*)&xs[(s + 1) & 1][T0 * 256 + lane * 4]       = g0;
            *(float4v*)&xs[(s + 1) & 1][(T0 + 1) * 256 + lane * 4] = g1;
        }
        __syncthreads();   // barrier B
        // 5. agg: D[k][c] += a[k][l] * x[c][l], K=16; bn straight from regs
        half4 aA = *(const half4*)&ah[(kt * 16 + m16) * 20 + 4 * q];
#pragma unroll
        for (int i = 0; i < 8; ++i)
            agc[i] = __builtin_amdgcn_mfma_f32_16x16x16f16(aA, bn[i], agc[i], 0, 0, 0);
    }

    // ---- epilogue: asum reduce (sl reused) + direct coalesced agg stores ----
    sl[wv * 64 + lane] = asum_reg;
    __syncthreads();
    if (t < 64) {
        float s_ = 0.f;
#pragma unroll
        for (int j = 0; j < 16; ++j) s_ += sl[j * 64 + t];
        asumP[((size_t)n * 4 + bx) * 64 + t] = s_;
    }
    float* ap = aggP + (((size_t)n * 4 + bx) * 64) * (size_t)C_;
#pragma unroll
    for (int i = 0; i < 8; ++i)
#pragma unroll
        for (int r = 0; r < 4; ++r)
            ap[(size_t)(kt * 16 + 4 * q + r) * C_ + (cs * 8 + i) * 16 + m16] = agc[i][r];
}

// ---------------------------------------------------------------------------
// kC: reduce 4 agg partials, vlad = agg - asum*cent, intra-normalize per
// (n,k) over C; global norm is exactly 8.  grid (16,64) = 1024 blocks,
// 256 thr, ONE k-row per wave.  float4 loads/stores.
// ---------------------------------------------------------------------------
__global__ __launch_bounds__(256) void kC(const float* __restrict__ aggP,
                                          const float* __restrict__ cent,
                                          const float* __restrict__ asumP,
                                          float* __restrict__ out) {
    __shared__ float asumS[4];
    const int t  = threadIdx.x;
    const int n  = blockIdx.y;
    const int k0 = blockIdx.x * 4;
    if (t < 4) {
        float s = 0.f;
        for (int j = 0; j < 4; ++j) s += asumP[((size_t)n * 4 + j) * 64 + k0 + t];
        asumS[t] = s;
    }
    __syncthreads();
    const int wv   = t >> 6;
    const int lane = t & 63;
    const int k    = k0 + wv;
    const float as = asumS[wv];
    const float* a0 = aggP + (((size_t)n * 4 + 0) * 64 + k) * C_;
    const float* a1 = aggP + (((size_t)n * 4 + 1) * 64 + k) * C_;
    const float* a2 = aggP + (((size_t)n * 4 + 2) * 64 + k) * C_;
    const float* a3 = aggP + (((size_t)n * 4 + 3) * 64 + k) * C_;
    const float* cp = cent + (size_t)k * C_;
    float4v v[2];
    float ss = 0.f;
#pragma unroll
    for (int j = 0; j < 2; ++j) {
        const int c = 4 * lane + 256 * j;
        float4v val = *(const float4v*)(a0 + c);
        val = val + *(const float4v*)(a1 + c);
        val = val + *(const float4v*)(a2 + c);
        val = val + *(const float4v*)(a3 + c);
        float4v c4 = *(const float4v*)(cp + c);
#pragma unroll
        for (int e = 0; e < 4; ++e) {
            val[e] -= as * c4[e];
            ss += val[e] * val[e];
        }
        v[j] = val;
    }
#pragma unroll
    for (int off = 32; off; off >>= 1) ss += __shfl_xor(ss, off, 64);
    const float scale = 1.f / (fmaxf(sqrtf(ss), EPS_) * 8.f);
    float* op = out + (size_t)n * (K_ * C_) + (size_t)k * C_;
#pragma unroll
    for (int j = 0; j < 2; ++j) {
        float4v o = v[j];
#pragma unroll
        for (int e = 0; e < 4; ++e) o[e] *= scale;
        *(float4v*)(op + 4 * lane + 256 * j) = o;
    }
}

extern "C" void kernel_launch(void* const* d_in, const int* in_sizes, int n_in,
                              void* d_out, int out_size, void* d_ws, size_t ws_size,
                              hipStream_t stream) {
    (void)in_sizes; (void)n_in; (void)out_size; (void)ws_size;
    const float* x    = (const float*)d_in[0];   // (64, 512, 28, 28) fp32
    const float* w    = (const float*)d_in[1];   // (64, 512) fp32
    const float* cent = (const float*)d_in[2];   // (64, 512) fp32
    float* out = (float*)d_out;                  // (64, 32768) fp32

    // ws: aggP f32 [64 n][4 bx][64 k][512 c] = 33.6 MB ; asumP f32 [64][4][64]
    // = 64 KB.  Total 33.7 MB (ws_size >= 46 MB known-good).
    char* base = (char*)d_ws;
    float* aggP  = (float*)base;
    float* asumP = aggP + (size_t)64 * 4 * 64 * 512;

    kF<<<dim3(4, 64), 1024, 0, stream>>>(x, w, aggP, asumP);
    kC<<<dim3(16, 64), 256, 0, stream>>>(aggP, cent, asumP, out);
}